// Round 9
// baseline (307.127 us; speedup 1.0000x reference)
//
#include <hip/hip_runtime.h>
#include <stdint.h>

// HashEmbedder (Instant-NGP hash grid), MI355X gfx950.
// R8 -> R9: R8 validated the model (k1=180us = 150-outstanding MSHR wall x
// ~250cyc L2 latency at 8 reqs/point-level). The request COUNT is reducible:
// pre-densify each level's accessed cell region (cells 0..R+1 per axis,
// 1.13M cells total) into dense 3D float4 arrays storing the z-pair
// (val[z], val[z+1]) -> each point-level needs 4 aligned float4 gathers
// instead of 8 float2. Densify pass ~2.3M gathers (~10us), amortized 28x.
// Slot->XCD map rebalanced: L7, L6 split across 2 XCDs each, paired with
// cheap L0/L1. Keeps SoA ws + transpose. Fallbacks: R8 path, then mono.

#define TABLE_SIZE (1u << 19)
#define TMASK (TABLE_SIZE - 1u)
#define P2 2654435761u
#define P3 805459861u

// Dense-grid geometry per level: S = R + 2 (bl can reach R at xc==1.0,
// corner bl+1 -> R+1). float4 entry = (val[z].x, val[z].y, val[z+1].x, val[z+1].y)
// Level:      0     1      2      3      4      5       6       7
// R:         16    20     25     32     40     50      64      80
// S:         18    22     27     34     42     52      66      82
// S^3:     5832 10648  19683  39304  74088 140608  287496  551368
// offset:     0  5832  16480  36163  75467 149555  290163  577659   (total 1129027)
#define DENSE_TOTAL 1129027

// ---------------- kernel 0: densify hashed tables into dense z-pair grids --
template<int S>
__device__ __forceinline__ void densify_one(const float2* __restrict__ tab,
                                            float4* __restrict__ dense,
                                            int e, int E)
{
    if (e >= E) return;
    const uint32_t cz = (uint32_t)(e % S);
    const int t = e / S;
    const uint32_t cy = (uint32_t)(t % S);
    const uint32_t cx = (uint32_t)(t / S);
    const uint32_t hb = cx ^ (cy * P2);
    const uint32_t h0 = (hb ^ (cz * P3)) & TMASK;
    const uint32_t h1 = (hb ^ ((cz + 1u) * P3)) & TMASK;
    const float2 a = tab[h0];
    const float2 b = tab[h1];
    dense[e] = make_float4(a.x, a.y, b.x, b.y);
}

__global__ __launch_bounds__(256) void densify_kernel(
    const float* __restrict__ tables, float4* __restrict__ dense)
{
    const int bid = (int)blockIdx.x;
    const int tid = (int)threadIdx.x;
    const float2* tabs = (const float2*)tables;
    // block ranges: ceil(S^3/256) cumulative: 23,65,142,296,586,1136,2260,4414
    if      (bid <   23) densify_one<18>(tabs + 0*(size_t)TABLE_SIZE, dense +      0, (bid       )*256 + tid,   5832);
    else if (bid <   65) densify_one<22>(tabs + 1*(size_t)TABLE_SIZE, dense +   5832, (bid -   23)*256 + tid,  10648);
    else if (bid <  142) densify_one<27>(tabs + 2*(size_t)TABLE_SIZE, dense +  16480, (bid -   65)*256 + tid,  19683);
    else if (bid <  296) densify_one<34>(tabs + 3*(size_t)TABLE_SIZE, dense +  36163, (bid -  142)*256 + tid,  39304);
    else if (bid <  586) densify_one<42>(tabs + 4*(size_t)TABLE_SIZE, dense +  75467, (bid -  296)*256 + tid,  74088);
    else if (bid < 1136) densify_one<52>(tabs + 5*(size_t)TABLE_SIZE, dense + 149555, (bid -  586)*256 + tid, 140608);
    else if (bid < 2260) densify_one<66>(tabs + 6*(size_t)TABLE_SIZE, dense + 290163, (bid - 1136)*256 + tid, 287496);
    else                 densify_one<82>(tabs + 7*(size_t)TABLE_SIZE, dense + 577659, (bid - 2260)*256 + tid, 551368);
}

// ---------------- kernel 1: dense-gather embed, SoA output ----------------
// grid = 8 * B, B = n/1024 blocks per slot; slot = bid&7 -> XCD (round-robin).
// Slot work map (rebalanced): s0/s1 = L7 halves + L0 halves; s2/s3 = L6
// halves + L1 halves; s4..s7 = L2..L5. Requires n % 2048 == 0.
__global__ __launch_bounds__(256, 4) void hash_embed_dense_kernel(
    const float* __restrict__ x, const float4* __restrict__ dense,
    float2* __restrict__ ws, int n)
{
    const uint32_t bid = blockIdx.x;
    const int slot = (int)(bid & 7u);
    const int j = (int)(bid >> 3);
    const int B = n >> 10;
    const int half = B >> 1;
    const int nh = n >> 1;

    int lvl, pbase;
    switch (slot) {
        case 0: if (j < half) { lvl = 7; pbase = j * 1024; }      else { lvl = 0; pbase = (j - half) * 1024; }      break;
        case 1: if (j < half) { lvl = 7; pbase = nh + j * 1024; } else { lvl = 0; pbase = nh + (j - half) * 1024; } break;
        case 2: if (j < half) { lvl = 6; pbase = j * 1024; }      else { lvl = 1; pbase = (j - half) * 1024; }      break;
        case 3: if (j < half) { lvl = 6; pbase = nh + j * 1024; } else { lvl = 1; pbase = nh + (j - half) * 1024; } break;
        case 4: lvl = 2; pbase = j * 1024; break;
        case 5: lvl = 3; pbase = j * 1024; break;
        case 6: lvl = 4; pbase = j * 1024; break;
        default: lvl = 5; pbase = j * 1024; break;
    }

    float R; int S; int O;
    switch (lvl) {
        case 0:  R = 16.f; S = 18; O = 0;      break;
        case 1:  R = 20.f; S = 22; O = 5832;   break;
        case 2:  R = 25.f; S = 27; O = 16480;  break;
        case 3:  R = 32.f; S = 34; O = 36163;  break;
        case 4:  R = 40.f; S = 42; O = 75467;  break;
        case 5:  R = 50.f; S = 52; O = 149555; break;
        case 6:  R = 64.f; S = 66; O = 290163; break;
        default: R = 80.f; S = 82; O = 577659; break;
    }
    const float g = 1.0f / R;
    const float4* __restrict__ D = dense + O;
    const int SS = S * S;

    const int base = pbase + (int)threadIdx.x;
    const int i0 = base, i1 = base + 256, i2 = base + 512, i3 = base + 768;

    const float px0 = x[3*i0+0], py0 = x[3*i0+1], pz0 = x[3*i0+2];
    const float px1 = x[3*i1+0], py1 = x[3*i1+1], pz1 = x[3*i1+2];
    const float px2 = x[3*i2+0], py2 = x[3*i2+1], pz2 = x[3*i2+2];
    const float px3 = x[3*i3+0], py3 = x[3*i3+1], pz3 = x[3*i3+2];

#define DPREP(k) \
    const float cx##k = fminf(fmaxf(px##k, 0.0f), 1.0f); \
    const float cy##k = fminf(fmaxf(py##k, 0.0f), 1.0f); \
    const float cz##k = fminf(fmaxf(pz##k, 0.0f), 1.0f); \
    const int bx##k = (int)floorf(cx##k * R); \
    const int by##k = (int)floorf(cy##k * R); \
    const int bz##k = (int)floorf(cz##k * R); \
    const float wx##k = (px##k - (float)bx##k * g) * R; \
    const float wy##k = (py##k - (float)by##k * g) * R; \
    const float wz##k = (pz##k - (float)bz##k * g) * R; \
    const int idx##k = (bx##k * S + by##k) * S + bz##k;

    DPREP(0) DPREP(1) DPREP(2) DPREP(3)

    // 16 float4 gathers (4/point); z-pair packed in each float4.
#define DGATHER(k) \
    const float4 d00##k = D[idx##k]; \
    const float4 d01##k = D[idx##k + S]; \
    const float4 d10##k = D[idx##k + SS]; \
    const float4 d11##k = D[idx##k + SS + S];

    DGATHER(0) DGATHER(1) DGATHER(2) DGATHER(3)

    // d00 = (e000, e001); d01 = (e010, e011); d10 = (e100, e101); d11 = (e110, e111)
#define DINTERP(k, dst) { \
    const float omx = 1.0f - wx##k, omy = 1.0f - wy##k, omz = 1.0f - wz##k; \
    const float c00a = d00##k.x * omx + d10##k.x * wx##k; \
    const float c00b = d00##k.y * omx + d10##k.y * wx##k; \
    const float c01a = d00##k.z * omx + d10##k.z * wx##k; \
    const float c01b = d00##k.w * omx + d10##k.w * wx##k; \
    const float c10a = d01##k.x * omx + d11##k.x * wx##k; \
    const float c10b = d01##k.y * omx + d11##k.y * wx##k; \
    const float c11a = d01##k.z * omx + d11##k.z * wx##k; \
    const float c11b = d01##k.w * omx + d11##k.w * wx##k; \
    const float c0a = c00a * omy + c10a * wy##k; \
    const float c0b = c00b * omy + c10b * wy##k; \
    const float c1a = c01a * omy + c11a * wy##k; \
    const float c1b = c01b * omy + c11b * wy##k; \
    dst.x = c0a * omz + c1a * wz##k; \
    dst.y = c0b * omz + c1b * wz##k; }

    float2 r0, r1, r2, r3;
    DINTERP(0, r0) DINTERP(1, r1) DINTERP(2, r2) DINTERP(3, r3)

    float2* __restrict__ wl = ws + (size_t)lvl * (size_t)n;
    wl[i0] = r0;
    wl[i1] = r1;
    wl[i2] = r2;
    wl[i3] = r3;
}

// ---------------- kernel 1 fallback (R8): hashed-gather embed, SoA --------
__global__ __launch_bounds__(256, 4) void hash_embed_soa_kernel(
    const float* __restrict__ x, const float* __restrict__ tables,
    float2* __restrict__ ws, int n)
{
    const uint32_t bid = blockIdx.x;
    const int l = (int)(bid & 7u);
    const int base = (int)(bid >> 3) * 1024 + (int)threadIdx.x;
    if (base >= n) return;

    float R;
    switch (l) {
        case 0: R = 16.f; break;
        case 1: R = 20.f; break;
        case 2: R = 25.f; break;
        case 3: R = 32.f; break;
        case 4: R = 40.f; break;
        case 5: R = 50.f; break;
        case 6: R = 64.f; break;
        default: R = 80.f; break;
    }
    const float g = 1.0f / R;
    const float2* __restrict__ tab =
        (const float2*)(tables) + (size_t)l * (size_t)TABLE_SIZE;

    const int i0 = base, i1 = base + 256, i2 = base + 512, i3 = base + 768;

    const float px0 = x[3*i0+0], py0 = x[3*i0+1], pz0 = x[3*i0+2];
    const float px1 = x[3*i1+0], py1 = x[3*i1+1], pz1 = x[3*i1+2];
    const float px2 = x[3*i2+0], py2 = x[3*i2+1], pz2 = x[3*i2+2];
    const float px3 = x[3*i3+0], py3 = x[3*i3+1], pz3 = x[3*i3+2];

#define PREP(k) \
    const float cx##k = fminf(fmaxf(px##k, 0.0f), 1.0f); \
    const float cy##k = fminf(fmaxf(py##k, 0.0f), 1.0f); \
    const float cz##k = fminf(fmaxf(pz##k, 0.0f), 1.0f); \
    const int bx##k = (int)floorf(cx##k * R); \
    const int by##k = (int)floorf(cy##k * R); \
    const int bz##k = (int)floorf(cz##k * R); \
    const float wx##k = (px##k - (float)bx##k * g) * R; \
    const float wy##k = (py##k - (float)by##k * g) * R; \
    const float wz##k = (pz##k - (float)bz##k * g) * R; \
    const uint32_t hx0##k = (uint32_t)bx##k; \
    const uint32_t hx1##k = hx0##k + 1u; \
    const uint32_t hy0##k = (uint32_t)by##k * P2; \
    const uint32_t hy1##k = hy0##k + P2; \
    const uint32_t hz0##k = (uint32_t)bz##k * P3; \
    const uint32_t hz1##k = hz0##k + P3;

    PREP(0) PREP(1) PREP(2) PREP(3)

#define GATHER(k) \
    const float2 e0##k = tab[(hx0##k ^ hy0##k ^ hz0##k) & TMASK]; \
    const float2 e1##k = tab[(hx0##k ^ hy0##k ^ hz1##k) & TMASK]; \
    const float2 e2##k = tab[(hx0##k ^ hy1##k ^ hz0##k) & TMASK]; \
    const float2 e3##k = tab[(hx0##k ^ hy1##k ^ hz1##k) & TMASK]; \
    const float2 e4##k = tab[(hx1##k ^ hy0##k ^ hz0##k) & TMASK]; \
    const float2 e5##k = tab[(hx1##k ^ hy0##k ^ hz1##k) & TMASK]; \
    const float2 e6##k = tab[(hx1##k ^ hy1##k ^ hz0##k) & TMASK]; \
    const float2 e7##k = tab[(hx1##k ^ hy1##k ^ hz1##k) & TMASK];

    GATHER(0) GATHER(1) GATHER(2) GATHER(3)

#define INTERP(k, dst) { \
    const float omx = 1.0f - wx##k, omy = 1.0f - wy##k, omz = 1.0f - wz##k; \
    const float c00a = e0##k.x * omx + e4##k.x * wx##k; \
    const float c00b = e0##k.y * omx + e4##k.y * wx##k; \
    const float c01a = e1##k.x * omx + e5##k.x * wx##k; \
    const float c01b = e1##k.y * omx + e5##k.y * wx##k; \
    const float c10a = e2##k.x * omx + e6##k.x * wx##k; \
    const float c10b = e2##k.y * omx + e6##k.y * wx##k; \
    const float c11a = e3##k.x * omx + e7##k.x * wx##k; \
    const float c11b = e3##k.y * omx + e7##k.y * wx##k; \
    const float c0a = c00a * omy + c10a * wy##k; \
    const float c0b = c00b * omy + c10b * wy##k; \
    const float c1a = c01a * omy + c11a * wy##k; \
    const float c1b = c01b * omy + c11b * wy##k; \
    dst.x = c0a * omz + c1a * wz##k; \
    dst.y = c0b * omz + c1b * wz##k; }

    float2 r0, r1, r2, r3;
    INTERP(0, r0) INTERP(1, r1) INTERP(2, r2) INTERP(3, r3)

    float2* __restrict__ wl = ws + (size_t)l * (size_t)n;
    wl[i0] = r0;
    wl[i1] = r1;
    wl[i2] = r2;
    wl[i3] = r3;
}

// ---------------- kernel 2: SoA -> AoS transpose --------------------------
__global__ __launch_bounds__(256) void soa_to_aos_kernel(
    const float2* __restrict__ ws, float* __restrict__ out, int n)
{
    const int i = blockIdx.x * 256 + threadIdx.x;
    if (i >= n) return;

    const float2 v0 = ws[0 * (size_t)n + i];
    const float2 v1 = ws[1 * (size_t)n + i];
    const float2 v2 = ws[2 * (size_t)n + i];
    const float2 v3 = ws[3 * (size_t)n + i];
    const float2 v4 = ws[4 * (size_t)n + i];
    const float2 v5 = ws[5 * (size_t)n + i];
    const float2 v6 = ws[6 * (size_t)n + i];
    const float2 v7 = ws[7 * (size_t)n + i];

    float4* __restrict__ op = (float4*)(out + (size_t)i * 16);
    op[0] = make_float4(v0.x, v0.y, v1.x, v1.y);
    op[1] = make_float4(v2.x, v2.y, v3.x, v3.y);
    op[2] = make_float4(v4.x, v4.y, v5.x, v5.y);
    op[3] = make_float4(v6.x, v6.y, v7.x, v7.y);
}

// ---------------- fallback: monolithic ------------------------------------
__global__ __launch_bounds__(256) void hash_embed_mono_kernel(
    const float* __restrict__ x, const float* __restrict__ tables,
    float* __restrict__ out, int n)
{
    const int i = blockIdx.x * 256 + threadIdx.x;
    if (i >= n) return;
    const float px = x[3*i+0], py = x[3*i+1], pz = x[3*i+2];
    const float cx = fminf(fmaxf(px, 0.0f), 1.0f);
    const float cy = fminf(fmaxf(py, 0.0f), 1.0f);
    const float cz = fminf(fmaxf(pz, 0.0f), 1.0f);
    const float resf[8] = {16.f,20.f,25.f,32.f,40.f,50.f,64.f,80.f};
    float o[16];
#pragma unroll
    for (int l = 0; l < 8; ++l) {
        const float R = resf[l], g = 1.0f / R;
        const int bx = (int)floorf(cx*R), by = (int)floorf(cy*R), bz = (int)floorf(cz*R);
        const float wx = (px - bx*g)*R, wy = (py - by*g)*R, wz = (pz - bz*g)*R;
        const uint32_t hx0 = (uint32_t)bx, hx1 = hx0+1u;
        const uint32_t hy0 = (uint32_t)by*P2, hy1 = hy0+P2;
        const uint32_t hz0 = (uint32_t)bz*P3, hz1 = hz0+P3;
        const float2* tab = (const float2*)(tables) + (size_t)l*(size_t)TABLE_SIZE;
        const float2 e000 = tab[(hx0^hy0^hz0)&TMASK], e001 = tab[(hx0^hy0^hz1)&TMASK];
        const float2 e010 = tab[(hx0^hy1^hz0)&TMASK], e011 = tab[(hx0^hy1^hz1)&TMASK];
        const float2 e100 = tab[(hx1^hy0^hz0)&TMASK], e101 = tab[(hx1^hy0^hz1)&TMASK];
        const float2 e110 = tab[(hx1^hy1^hz0)&TMASK], e111 = tab[(hx1^hy1^hz1)&TMASK];
        const float omx = 1.f-wx, omy = 1.f-wy, omz = 1.f-wz;
        const float c00a = e000.x*omx + e100.x*wx, c00b = e000.y*omx + e100.y*wx;
        const float c01a = e001.x*omx + e101.x*wx, c01b = e001.y*omx + e101.y*wx;
        const float c10a = e010.x*omx + e110.x*wx, c10b = e010.y*omx + e110.y*wx;
        const float c11a = e011.x*omx + e111.x*wx, c11b = e011.y*omx + e111.y*wx;
        const float c0a = c00a*omy + c10a*wy, c0b = c00b*omy + c10b*wy;
        const float c1a = c01a*omy + c11a*wy, c1b = c01b*omy + c11b*wy;
        o[2*l+0] = c0a*omz + c1a*wz;
        o[2*l+1] = c0b*omz + c1b*wz;
    }
    float4* op = (float4*)(out + (size_t)i * 16);
    op[0] = make_float4(o[0],o[1],o[2],o[3]);
    op[1] = make_float4(o[4],o[5],o[6],o[7]);
    op[2] = make_float4(o[8],o[9],o[10],o[11]);
    op[3] = make_float4(o[12],o[13],o[14],o[15]);
}

extern "C" void kernel_launch(void* const* d_in, const int* in_sizes, int n_in,
                              void* d_out, int out_size, void* d_ws, size_t ws_size,
                              hipStream_t stream) {
    const float* x = (const float*)d_in[0];
    const float* tables = (const float*)d_in[1];
    float* out = (float*)d_out;
    const int n = in_sizes[0] / 3;  // 1048576 points

    const size_t soa_bytes = (size_t)8 * (size_t)n * sizeof(float2);      // 64 MB
    const size_t dense_bytes = (size_t)DENSE_TOTAL * sizeof(float4);      // ~17.2 MB
    float2* ws = (float2*)d_ws;

    if (ws_size >= soa_bytes + dense_bytes && (n % 2048) == 0) {
        float4* dense = (float4*)((char*)d_ws + soa_bytes);
        densify_kernel<<<4414, 256, 0, stream>>>(tables, dense);
        const int B = n / 1024;
        hash_embed_dense_kernel<<<B * 8, 256, 0, stream>>>(x, dense, ws, n);
        soa_to_aos_kernel<<<(n + 255) / 256, 256, 0, stream>>>(ws, out, n);
    } else if (ws_size >= soa_bytes && (n % 1024) == 0) {
        const int blocks_per_level = n / 1024;
        hash_embed_soa_kernel<<<blocks_per_level * 8, 256, 0, stream>>>(x, tables, ws, n);
        soa_to_aos_kernel<<<(n + 255) / 256, 256, 0, stream>>>(ws, out, n);
    } else {
        hash_embed_mono_kernel<<<(n + 255) / 256, 256, 0, stream>>>(x, tables, out, n);
    }
}